// Round 5
// baseline (680.464 us; speedup 1.0000x reference)
//
#include <hip/hip_runtime.h>

// GRU: B=256, T=2048, I=2, H=128. One workgroup (4 waves) per batch element.
// R21: i8 MFMA (R20) with 4 waves instead of 8 -- halve the LDS read drain.
// Model (calibrated R17-R20, clock ~1.8GHz at this utilization): step 535cyc
// = 160 VALU-issue + 74 matrix + ~300 exposed. Largest exposed term: LDS
// read drain = 16x ds_read_b128 (8 waves x 2) at ~12cyc on ONE pipe (~190)
// + ~120 base latency, all at barrier release. 4 waves -> 8 reads (~96 cyc
// saved), smaller barrier skew. Cost: 12 MFMA/wave (issue hidden across
// SIMDs), select tree back to 21 cndmask (+1 chain level). If this is FLAT,
// broadcast reads are deduped and the drain model is falsified.
// Kept from R20: i8 16x16x64 MFMA, K=64 x 2-deep chains, exact-bound
// symmetric quant (|h|<1, |W|<1/sqrt(128); h err <= 1/254), i32 accum,
// dequant folded into post-select fma, exp2/rcp gates, x in LDS + t+1
// prefetch, fp32 h recurrence, 1 barrier/step.
// Micro: omz/zh precomputed during n-chain -> only 1 fma after n.
// Falsified: pre-barrier pipeline tail (R19 +94ns, no barrier slack in
// symmetric schedule); pairing elements (useless: wall = 2048 x chain);
// fp8 h exchange (e4m3 3-bit mantissa -> ~14x worse h error, absmax risk).

#define BB 256
#define TT 2048
#define HH 128
#define NT 256

typedef int v4i __attribute__((ext_vector_type(4)));

__global__ __launch_bounds__(NT, 1) void gru_seq_kernel(
    const float* __restrict__ x,        // [B, T, 2]
    const int*   __restrict__ lengths,  // [B]
    const float* __restrict__ W_ih,     // [384, 2]
    const float* __restrict__ W_hh,     // [384, 128]
    const float* __restrict__ b_ih,     // [384]
    const float* __restrict__ b_hh,     // [384]
    const float* __restrict__ head_w,   // [128]
    const float* __restrict__ head_b,   // [1]
    float* __restrict__ out)            // [B]
{
    __shared__ __align__(16) float x_lds[(TT + 1) * 2];      // 16 KB (+prefetch pad)
    __shared__ __align__(16) signed char h_lds[2][HH];       // 2 x 128 B, dbuf
    __shared__ float red[HH];

    const int tid = threadIdx.x;
    const int w    = tid >> 6;       // wave 0..3: owns units [32w, 32w+32)
    const int l    = tid & 63;
    const int lg   = l >> 4;         // k-slice (16 i8) / D-row group
    const int m    = l & 15;         // A row within tile = D col (replica id)
    const int js   = m & 1;          // 16-row half-tile select
    const int rsel = (m >> 1) & 3;   // D reg select
    const int rep  = m >> 3;         // replica 0/1; rep==0 produces
    const int b  = blockIdx.x;
    const int len = lengths[b];

    const float S_RZ = -1.4426950408889634f;   // -log2(e)
    const float S_N  =  2.8853900817779268f;   //  2*log2(e)
    const float WMAX = 0.08838834764831845f;   // 1/sqrt(128), strict |W_hh| bound
    const float QW   = 127.0f / WMAX;          // weight quant scale
    const float CONV = WMAX / 16129.0f;        // dequant: wmax/(127*127)
    const float C_RZ = S_RZ * CONV;
    const float C_N  = S_N * CONV;

    // --- A-frags: afrag[g*2+jp][c] = int8-packed
    //     W_hh[128g + 32w + 16jp + m][64c + 16lg + 4r + j], dword r byte j.
    v4i afrag[6][2];
    #pragma unroll
    for (int g = 0; g < 3; ++g) {
        #pragma unroll
        for (int jp = 0; jp < 2; ++jp) {
            const float* Wr = W_hh + (size_t)(128 * g + 32 * w + 16 * jp + m) * HH;
            #pragma unroll
            for (int c = 0; c < 2; ++c) {
                unsigned q[4];
                #pragma unroll
                for (int r = 0; r < 4; ++r) {
                    q[r] = 0u;
                    #pragma unroll
                    for (int j = 0; j < 4; ++j) {
                        const float wv = Wr[64 * c + 16 * lg + 4 * r + j];
                        const unsigned bq = ((unsigned)fmaf(wv, QW, 256.5f)) & 0xFFu;
                        q[r] |= bq << (8 * j);
                    }
                }
                afrag[g * 2 + jp][c] = (v4i){(int)q[0], (int)q[1], (int)q[2], (int)q[3]};
            }
        }
    }

    // --- this lane's unit and per-unit scalars (xp/bias terms, prescaled) ---
    const int u = 32 * w + 16 * js + 4 * lg + rsel;
    const float cr0 = S_RZ * W_ih[u * 2];
    const float cr1 = S_RZ * W_ih[u * 2 + 1];
    const float crb = S_RZ * (b_ih[u] + b_hh[u]);
    const float cz0 = S_RZ * W_ih[(HH + u) * 2];
    const float cz1 = S_RZ * W_ih[(HH + u) * 2 + 1];
    const float czb = S_RZ * (b_ih[HH + u] + b_hh[HH + u]);
    const float cn0 = S_N * W_ih[(2 * HH + u) * 2];
    const float cn1 = S_N * W_ih[(2 * HH + u) * 2 + 1];
    const float cnbi = S_N * b_ih[2 * HH + u];
    const float cnbh = S_N * b_hh[2 * HH + u];
    const float hw   = head_w[u];

    // --- stage x[b] into LDS (float4, coalesced) ---
    {
        const float4* xb4 = (const float4*)(x + (size_t)b * TT * 2);
        float4* xl4 = (float4*)x_lds;
        #pragma unroll
        for (int i = tid; i < TT * 2 / 4; i += NT) xl4[i] = xb4[i];
    }
    if (tid == 0) { x_lds[TT * 2] = 0.f; x_lds[TT * 2 + 1] = 0.f; }
    for (int i = tid; i < 2 * HH; i += NT) ((signed char*)h_lds)[i] = 0;

    __syncthreads();

    float h_reg = 0.0f;              // fp32 h[u]; maintained in both replicas
    int buf = 0;
    const float2* x2 = (const float2*)x_lds;
    float2 xt = x2[0];
    const v4i zero = {0, 0, 0, 0};

    for (int t = 0; t < len; ++t) {
        // h B-frags: 2 x ds_read_b128 (16-lane same-address broadcast)
        const signed char* hb = h_lds[buf];
        const v4i B0 = *(const v4i*)(hb + 16 * lg);        // k 0..63
        const v4i B1 = *(const v4i*)(hb + 64 + 16 * lg);   // k 64..127

        const float2 xt_next = x2[t + 1];   // prefetch (pad-safe at t = len-1)

        // xp terms: independent of h, hide under MFMA phase
        const float xpr = fmaf(cr0, xt.x, fmaf(cr1, xt.y, crb));
        const float xpz = fmaf(cz0, xt.x, fmaf(cz1, xt.y, czb));
        const float xpn = fmaf(cn0, xt.x, fmaf(cn1, xt.y, cnbi));

        // 12 MFMAs: 6 tiles (3 gates x 2 half-tiles) x 2-deep K-chain, 6-way ILP
        v4i acc[6];
        #pragma unroll
        for (int j = 0; j < 6; ++j)
            acc[j] = __builtin_amdgcn_mfma_i32_16x16x64_i8(afrag[j][0], B0, zero, 0, 0, 0);
        #pragma unroll
        for (int j = 0; j < 6; ++j)
            acc[j] = __builtin_amdgcn_mfma_i32_16x16x64_i8(afrag[j][1], B1, acc[j], 0, 0, 0);

        // de-replication: 7 cndmask per gate (reg-select, then half-tile)
        int sR, sZ, sN;
        #define PICK(g, dst) do {                                            \
            const int _a01 = (rsel & 1) ? acc[2*(g)][1]   : acc[2*(g)][0];   \
            const int _a23 = (rsel & 1) ? acc[2*(g)][3]   : acc[2*(g)][2];   \
            const int _va  = (rsel & 2) ? _a23 : _a01;                       \
            const int _b01 = (rsel & 1) ? acc[2*(g)+1][1] : acc[2*(g)+1][0]; \
            const int _b23 = (rsel & 1) ? acc[2*(g)+1][3] : acc[2*(g)+1][2]; \
            const int _vb  = (rsel & 2) ? _b23 : _b01;                       \
            (dst) = js ? _vb : _va;                                          \
        } while (0)
        PICK(0, sR); PICK(1, sZ); PICK(2, sN);
        #undef PICK

        // gate chain (dequant+prescale fused; omz/zh precomputed so only
        // ONE fma follows n):
        // sigmoid(v) = rcp(1+exp2(S_RZ*v)); tanh(y) = 1 - 2*rcp(1+exp2(S_N*y))
        const float ar = fmaf((float)sR, C_RZ, xpr);
        const float az = fmaf((float)sZ, C_RZ, xpz);
        const float r  = __builtin_amdgcn_rcpf(1.f + __builtin_amdgcn_exp2f(ar));
        const float z  = __builtin_amdgcn_rcpf(1.f + __builtin_amdgcn_exp2f(az));
        const float omz = 1.f - z;
        const float zh  = z * h_reg;
        const float an = fmaf((float)sN, C_N, cnbh);
        const float uu = __builtin_amdgcn_exp2f(fmaf(r, an, xpn));
        const float n  = fmaf(-2.f, __builtin_amdgcn_rcpf(1.f + uu), 1.f);
        const float h_new = fmaf(n, omz, zh);
        h_reg = h_new;

        // quantize h -> i8 and publish (|h|<1 strictly; +256.5 = round-half,
        // low byte = two's complement). rep==0: 4 lanes/dword byte-merge, free.
        if (rep == 0) {
            const unsigned hq = (unsigned)fmaf(h_new, 127.0f, 256.5f);
            h_lds[buf ^ 1][u] = (signed char)(hq & 0xFFu);
        }
        __syncthreads();
        buf ^= 1;
        xt = xt_next;
    }

    // --- head: out[b] = dot(h, head_w) + head_b ---
    if (rep == 0) red[u] = h_reg * hw;
    __syncthreads();
    if (tid < 64) {
        float v = red[tid] + red[tid + 64];
        #pragma unroll
        for (int off = 32; off > 0; off >>= 1) v += __shfl_xor(v, off, 64);
        if (tid == 0) out[b] = v + head_b[0];
    }
}

extern "C" void kernel_launch(void* const* d_in, const int* in_sizes, int n_in,
                              void* d_out, int out_size, void* d_ws, size_t ws_size,
                              hipStream_t stream) {
    const float* x      = (const float*)d_in[0];
    const int*   len    = (const int*)  d_in[1];
    const float* W_ih   = (const float*)d_in[2];
    const float* W_hh   = (const float*)d_in[3];
    const float* b_ih   = (const float*)d_in[4];
    const float* b_hh   = (const float*)d_in[5];
    const float* head_w = (const float*)d_in[6];
    const float* head_b = (const float*)d_in[7];
    float* out = (float*)d_out;

    gru_seq_kernel<<<BB, NT, 0, stream>>>(x, len, W_ih, W_hh, b_ih, b_hh,
                                          head_w, head_b, out);
}